// Round 1
// baseline (71.931 us; speedup 1.0000x reference)
//
#include <hip/hip_runtime.h>

// Path signature, depth 4, D=8. Output layout (matches JAX flatten):
//   s1[8] | s2[64] (i*8+j) | s3[512] (i*64+j*8+k) | s4[4096] (i*512+j*64+k*8+l)
#define SIGLEN 4680
#define S1OFF 0
#define S2OFF 8
#define S3OFF 72
#define S4OFF 584
#define MAXROWS 513  // supports chunk len <= 512 increments

// ---------------------------------------------------------------------------
// Kernel 1: per-chunk sequential signature via streaming chen(S, exp(dx)).
// Block = 256 threads. s1,s2,s3 double-buffered in LDS; s4 in regs (16/thr).
// Thread t owns: s4 flat [16t,16t+16), s3 flat {2t,2t+1}, s2[t] (t<64), s1[t] (t<8).
// Update (old lower levels, a = state, e_k = dx^k/k!):
//   s4[ijkl] += dx[l] * ( a3[ijk] + dx[k]*( a2[ij]/2 + dx[j]*(a1[i]/6 + dx[i]/24) ) )
//   s3[jkl]  += dx[l] * ( a2[jk] + dx[k]*( a1[j]/2 + dx[j]/6 ) )
//   s2[kl]   += dx[l] * ( a1[k] + dx[k]/2 )
//   s1[l]    += dx[l]
// ---------------------------------------------------------------------------
__global__ __launch_bounds__(256) void sig_chunk(const float* __restrict__ path,
                                                 float* __restrict__ partials,
                                                 int nInc, int nChunks) {
  __shared__ float lds_path[MAXROWS * 8];
  __shared__ float st[2][584];
  const int t = threadIdx.x;
  const int c = blockIdx.x;
  const long start = ((long)c * nInc) / nChunks;
  const long end = ((long)(c + 1) * nInc) / nChunks;
  const int len = (int)(end - start);

  const int nload = (len + 1) * 8;
  for (int idx = t; idx < nload; idx += 256)
    lds_path[idx] = path[start * 8 + idx];
  for (int idx = t; idx < 584; idx += 256)
    st[0][idx] = 0.0f;
  float s4[16];
#pragma unroll
  for (int e = 0; e < 16; ++e) s4[e] = 0.0f;
  __syncthreads();

  const int i_idx = t >> 5;          // i of owned s4 elems (= j of owned s3)
  const int ij_idx = t >> 2;         // ij of owned s4 (= jk of owned s3)
  const int j_idx = ij_idx & 7;      // j of owned s4 (= k of owned s3)
  const int k0 = 2 * (t & 3);        // k of group 0 (group 1: k0+1)

  int p = 0;
  for (int it = 0; it < len; ++it) {
    float dx[8];
#pragma unroll
    for (int m = 0; m < 8; ++m)
      dx[m] = lds_path[(it + 1) * 8 + m] - lds_path[it * 8 + m];

    const float a1  = st[p][S1OFF + i_idx];
    const float a2  = st[p][S2OFF + ij_idx];
    const float a30 = st[p][S3OFF + 2 * t];
    const float a31 = st[p][S3OFF + 2 * t + 1];
    float s1k = 0.f, a2own = 0.f, a1own = 0.f;
    if (t < 64) { s1k = st[p][S1OFF + (t >> 3)]; a2own = st[p][S2OFF + t]; }
    if (t < 8)  { a1own = st[p][S1OFF + t]; }

    const float dxi = dx[i_idx];
    const float dxj = dx[j_idx];
    const float dxk0 = dx[k0];
    const float dxk1 = dx[k0 + 1];

    // level 4 (registers)
    const float inner = 0.5f * a2 + dxj * ((1.0f / 6.0f) * a1 + (1.0f / 24.0f) * dxi);
    const float c0 = a30 + dxk0 * inner;
    const float c1 = a31 + dxk1 * inner;
#pragma unroll
    for (int l = 0; l < 8; ++l) s4[l]     += c0 * dx[l];
#pragma unroll
    for (int l = 0; l < 8; ++l) s4[8 + l] += c1 * dx[l];

    // levels 3..1 -> other LDS buffer
    const int q = p ^ 1;
    const float common3 = a2 + dxj * (0.5f * a1 + (1.0f / 6.0f) * dxi);
    st[q][S3OFF + 2 * t]     = a30 + common3 * dxk0;
    st[q][S3OFF + 2 * t + 1] = a31 + common3 * dxk1;
    if (t < 64)
      st[q][S2OFF + t] = a2own + dx[t & 7] * (s1k + 0.5f * dx[t >> 3]);
    if (t < 8)
      st[q][S1OFF + t] = a1own + dx[t];
    __syncthreads();
    p = q;
  }

  float* outp = partials + (long)c * SIGLEN;
  for (int idx = t; idx < 584; idx += 256) outp[idx] = st[p][idx];
#pragma unroll
  for (int e = 0; e < 16; ++e) outp[S4OFF + 16 * t + e] = s4[e];
}

// ---------------------------------------------------------------------------
// Kernel 2/3: left-fold full Chen product of nPer consecutive signatures.
//   c4 = a4 + b4 + a1(x)b3 + a2(x)b2 + a3(x)b1
//   c3 = a3 + b3 + a1(x)b2 + a2(x)b1
//   c2 = a2 + b2 + a1(x)b1
//   c1 = a1 + b1
// Same per-thread ownership as kernel 1. a-state: LDS double-buffer + regs.
// ---------------------------------------------------------------------------
__global__ __launch_bounds__(256) void sig_combine(const float* __restrict__ in,
                                                   float* __restrict__ outp,
                                                   int nPer) {
  __shared__ float st[2][584];
  __shared__ float bs[584];
  const int t = threadIdx.x;
  const int b = blockIdx.x;
  const float* base = in + (long)b * nPer * SIGLEN;

  for (int idx = t; idx < 584; idx += 256) st[0][idx] = base[idx];
  float a4[16];
#pragma unroll
  for (int e = 0; e < 16; ++e) a4[e] = base[S4OFF + 16 * t + e];
  __syncthreads();

  int p = 0;
  for (int m = 1; m < nPer; ++m) {
    const float* B = base + (long)m * SIGLEN;
    for (int idx = t; idx < 584; idx += 256) bs[idx] = B[idx];
    float b4[16];
#pragma unroll
    for (int e = 0; e < 16; ++e) b4[e] = B[S4OFF + 16 * t + e];
    __syncthreads();  // bs ready

    const float a1  = st[p][S1OFF + (t >> 5)];
    const float a2  = st[p][S2OFF + (t >> 2)];
    const float a30 = st[p][S3OFF + 2 * t];
    const float a31 = st[p][S3OFF + 2 * t + 1];
#pragma unroll
    for (int e = 0; e < 16; ++e) {
      const float a3v = (e < 8) ? a30 : a31;
      a4[e] += b4[e] + a1 * bs[S3OFF + (t & 31) * 16 + e]
                     + a2 * bs[S2OFF + (t & 3) * 16 + e]
                     + a3v * bs[S1OFF + (e & 7)];
    }
    const int q = p ^ 1;
#pragma unroll
    for (int u = 0; u < 2; ++u) {
      const int f = 2 * t + u;
      st[q][S3OFF + f] = st[p][S3OFF + f] + bs[S3OFF + f]
                       + a1 * bs[S2OFF + (f & 63)] + a2 * bs[S1OFF + (f & 7)];
    }
    if (t < 64)
      st[q][S2OFF + t] = st[p][S2OFF + t] + bs[S2OFF + t]
                       + st[p][S1OFF + (t >> 3)] * bs[S1OFF + (t & 7)];
    if (t < 8)
      st[q][S1OFF + t] = st[p][S1OFF + t] + bs[S1OFF + t];
    __syncthreads();  // st[q] ready
    p ^= 1;
  }

  float* o = outp + (long)b * SIGLEN;
  for (int idx = t; idx < 584; idx += 256) o[idx] = st[p][idx];
#pragma unroll
  for (int e = 0; e < 16; ++e) o[S4OFF + 16 * t + e] = a4[e];
}

extern "C" void kernel_launch(void* const* d_in, const int* in_sizes, int n_in,
                              void* d_out, int out_size, void* d_ws, size_t ws_size,
                              hipStream_t stream) {
  const float* path = (const float*)d_in[0];
  float* out = (float*)d_out;
  const int L = in_sizes[0] / 8;
  const int nInc = L - 1;

  // Tier by workspace capacity (floats needed: (N1 + grid2) * SIGLEN).
  int N1, grid2;
  if (ws_size >= (size_t)272 * SIGLEN * 4)      { N1 = 256; grid2 = 16; }
  else if (ws_size >= (size_t)72 * SIGLEN * 4)  { N1 = 64;  grid2 = 8;  }
  else                                          { N1 = 16;  grid2 = 4;  }

  float* partials = (float*)d_ws;
  float* stage2 = partials + (size_t)N1 * SIGLEN;

  sig_chunk<<<N1, 256, 0, stream>>>(path, partials, nInc, N1);
  sig_combine<<<grid2, 256, 0, stream>>>(partials, stage2, N1 / grid2);
  sig_combine<<<1, 256, 0, stream>>>(stage2, out, grid2);
}

// Round 2
// 55.756 us; speedup vs baseline: 1.2901x; 1.2901x over previous
//
#include <hip/hip_runtime.h>

// Path signature, depth 4, D=8. Output layout (matches JAX flatten):
//   s1[8] | s2[64] (i*8+j) | s3[512] (i*64+j*8+k) | s4[4096] (i*512+j*64+k*8+l)
//
// Thread-private-state decomposition: thread t (of 256) owns
//   s4 flat [16t, 16t+16)  -> indices (i = t>>5, j = (t>>2)&7, k in {k0,k0+1}, l=0..7)
//   s3 flat {2t, 2t+1}     -> (i, j, k0..k0+1)   [same i,j!]
//   s2 flat  t>>2          -> (i, j)             [same i,j!]
//   s1 flat  t>>5          -> (i)                [same i!]
// Because the index prefixes nest, the running lower-level values each thread
// needs (a1[i], a2[ij], a3[ij,k0..k0+1]) can be maintained entirely in
// registers with no cross-thread communication -> no barriers in the scan.
#define SIGLEN 4680
#define S1OFF 0
#define S2OFF 8
#define S3OFF 72
#define S4OFF 584
#define MAXROWS 513  // supports chunk len <= 512 increments (ws fallback tiers)

// ---------------------------------------------------------------------------
// Kernel 1: per-chunk signature, streaming chen(S, exp(dx)). Barrier-free loop.
// ---------------------------------------------------------------------------
__global__ __launch_bounds__(256) void sig_chunk(const float* __restrict__ path,
                                                 float* __restrict__ partials,
                                                 int nInc, int nChunks) {
  __shared__ float4 pl[MAXROWS * 2];        // staged path rows
  __shared__ float4 dv[(MAXROWS - 1) * 2];  // increment rows
  const int t = threadIdx.x;
  const int c = blockIdx.x;
  const long start = ((long)c * nInc) / nChunks;
  const long end = ((long)(c + 1) * nInc) / nChunks;
  const int len = (int)(end - start);

  const float4* gp = (const float4*)(path + start * 8);
  const int nvec = (len + 1) * 2;
  for (int idx = t; idx < nvec; idx += 256) pl[idx] = gp[idx];
  __syncthreads();
  for (int idx = t; idx < len * 2; idx += 256) {
    float4 a = pl[idx + 2], b = pl[idx];
    dv[idx] = make_float4(a.x - b.x, a.y - b.y, a.z - b.z, a.w - b.w);
  }
  __syncthreads();

  const int i_idx = t >> 5;
  const int j_idx = (t >> 2) & 7;
  const int k0 = 2 * (t & 3);
  const float* dvf = (const float*)dv;

  float s4[16];
#pragma unroll
  for (int e = 0; e < 16; ++e) s4[e] = 0.f;
  float a1 = 0.f, a2 = 0.f, a30 = 0.f, a31 = 0.f;

  for (int it = 0; it < len; ++it) {
    // broadcast reads (lane-uniform address) for the full dx row
    const float4 d0 = dv[it * 2], d1 = dv[it * 2 + 1];
    const float dxl[8] = {d0.x, d0.y, d0.z, d0.w, d1.x, d1.y, d1.z, d1.w};
    // per-lane scalar reads for runtime-indexed components (avoids scratch)
    const float dxi = dvf[it * 8 + i_idx];
    const float dxj = dvf[it * 8 + j_idx];
    const float2 dkk = *(const float2*)(dvf + it * 8 + k0);

    // level 4 (uses old a3,a2,a1)
    const float inner = 0.5f * a2 + dxj * ((1.f / 6.f) * a1 + (1.f / 24.f) * dxi);
    const float c0 = a30 + dkk.x * inner;
    const float c1 = a31 + dkk.y * inner;
#pragma unroll
    for (int l = 0; l < 8; ++l) s4[l] += c0 * dxl[l];
#pragma unroll
    for (int l = 0; l < 8; ++l) s4[8 + l] += c1 * dxl[l];
    // level 3 (old a2,a1), level 2 (old a1), level 1
    const float common3 = a2 + dxj * (0.5f * a1 + (1.f / 6.f) * dxi);
    a30 += common3 * dkk.x;
    a31 += common3 * dkk.y;
    a2 += dxj * (a1 + 0.5f * dxi);
    a1 += dxi;
  }

  float* o = partials + (long)c * SIGLEN;
  if ((t & 31) == 0) o[S1OFF + i_idx] = a1;
  if ((t & 3) == 0) o[S2OFF + (t >> 2)] = a2;
  *(float2*)(o + S3OFF + 2 * t) = make_float2(a30, a31);
  float4* o4 = (float4*)(o + S4OFF + 16 * t);
#pragma unroll
  for (int r = 0; r < 4; ++r)
    o4[r] = make_float4(s4[4 * r], s4[4 * r + 1], s4[4 * r + 2], s4[4 * r + 3]);
}

// ---------------------------------------------------------------------------
// Kernel 2/3: left-fold full Chen product of nPer consecutive signatures.
//   c4 = a4 + b4 + a1(x)b3 + a2(x)b2 + a3(x)b1
//   c3 = a3 + b3 + a1(x)b2 + a2(x)b1
//   c2 = a2 + b2 + a1(x)b1 ; c1 = a1 + b1
// A-state fully register-private; B read straight from global (L2-resident).
// No LDS, no barriers.
// ---------------------------------------------------------------------------
__global__ __launch_bounds__(256) void sig_combine(const float* __restrict__ in,
                                                   float* __restrict__ outp,
                                                   int nPer) {
  const int t = threadIdx.x;
  const int b = blockIdx.x;
  const float* base = in + (long)b * nPer * SIGLEN;
  const int i_idx = t >> 5;
  const int j_idx = (t >> 2) & 7;
  const int k0 = 2 * (t & 3);

  float s4[16];
  {
    const float4* p4 = (const float4*)(base + S4OFF + 16 * t);
#pragma unroll
    for (int r = 0; r < 4; ++r) {
      float4 v = p4[r];
      s4[4 * r] = v.x; s4[4 * r + 1] = v.y; s4[4 * r + 2] = v.z; s4[4 * r + 3] = v.w;
    }
  }
  float a1 = base[S1OFF + i_idx];
  float a2 = base[S2OFF + (t >> 2)];
  const float2 a3i = *(const float2*)(base + S3OFF + 2 * t);
  float a30 = a3i.x, a31 = a3i.y;

  for (int m = 1; m < nPer; ++m) {
    const float* B = base + (long)m * SIGLEN;
    // b1: full row in named regs (compile-time access) + runtime-indexed scalars
    const float4 b1lo = *(const float4*)(B + S1OFF);
    const float4 b1hi = *(const float4*)(B + S1OFF + 4);
    const float b1v[8] = {b1lo.x, b1lo.y, b1lo.z, b1lo.w, b1hi.x, b1hi.y, b1hi.z, b1hi.w};
    const float b1i = B[S1OFF + i_idx];
    const float b1j = B[S1OFF + j_idx];
    const float2 b1k = *(const float2*)(B + S1OFF + k0);
    const float b2own = B[S2OFF + (t >> 2)];
    const float2 b2p = *(const float2*)(B + S2OFF + ((2 * t) & 63));
    const float2 b3p = *(const float2*)(B + S3OFF + 2 * t);
    float b2r[16], b3r[16], b4r[16];
    const float4* q2 = (const float4*)(B + S2OFF + 16 * (t & 3));
    const float4* q3 = (const float4*)(B + S3OFF + 16 * (t & 31));
    const float4* q4 = (const float4*)(B + S4OFF + 16 * t);
#pragma unroll
    for (int r = 0; r < 4; ++r) {
      const float4 v2 = q2[r], v3 = q3[r], v4 = q4[r];
      b2r[4 * r] = v2.x; b2r[4 * r + 1] = v2.y; b2r[4 * r + 2] = v2.z; b2r[4 * r + 3] = v2.w;
      b3r[4 * r] = v3.x; b3r[4 * r + 1] = v3.y; b3r[4 * r + 2] = v3.z; b3r[4 * r + 3] = v3.w;
      b4r[4 * r] = v4.x; b4r[4 * r + 1] = v4.y; b4r[4 * r + 2] = v4.z; b4r[4 * r + 3] = v4.w;
    }
    // c4 first (uses old a1,a2,a30,a31)
#pragma unroll
    for (int e = 0; e < 16; ++e) {
      const float a3v = (e < 8) ? a30 : a31;
      s4[e] += b4r[e] + a1 * b3r[e] + a2 * b2r[e] + a3v * b1v[e & 7];
    }
    // c3 (old a1,a2), c2 (old a1), c1 — strictly top-down, safe in place
    a30 += b3p.x + a1 * b2p.x + a2 * b1k.x;
    a31 += b3p.y + a1 * b2p.y + a2 * b1k.y;
    a2 += b2own + a1 * b1j;
    a1 += b1i;
  }

  float* o = outp + (long)b * SIGLEN;
  if ((t & 31) == 0) o[S1OFF + i_idx] = a1;
  if ((t & 3) == 0) o[S2OFF + (t >> 2)] = a2;
  *(float2*)(o + S3OFF + 2 * t) = make_float2(a30, a31);
  float4* o4 = (float4*)(o + S4OFF + 16 * t);
#pragma unroll
  for (int r = 0; r < 4; ++r)
    o4[r] = make_float4(s4[4 * r], s4[4 * r + 1], s4[4 * r + 2], s4[4 * r + 3]);
}

extern "C" void kernel_launch(void* const* d_in, const int* in_sizes, int n_in,
                              void* d_out, int out_size, void* d_ws, size_t ws_size,
                              hipStream_t stream) {
  const float* path = (const float*)d_in[0];
  float* out = (float*)d_out;
  const int L = in_sizes[0] / 8;
  const int nInc = L - 1;

  // Tier by workspace capacity (floats needed: (N1 + grid2) * SIGLEN).
  int N1, grid2;
  if (ws_size >= (size_t)272 * SIGLEN * 4)      { N1 = 256; grid2 = 16; }
  else if (ws_size >= (size_t)72 * SIGLEN * 4)  { N1 = 64;  grid2 = 8;  }
  else                                          { N1 = 16;  grid2 = 4;  }

  float* partials = (float*)d_ws;
  float* stage2 = partials + (size_t)N1 * SIGLEN;

  sig_chunk<<<N1, 256, 0, stream>>>(path, partials, nInc, N1);
  sig_combine<<<grid2, 256, 0, stream>>>(partials, stage2, N1 / grid2);
  sig_combine<<<1, 256, 0, stream>>>(stage2, out, grid2);
}